// Round 6
// baseline (522.097 us; speedup 1.0000x reference)
//
#include <hip/hip_runtime.h>
#include <math.h>

#define D 64

typedef __attribute__((ext_vector_type(8))) short frag_ab;
typedef __attribute__((ext_vector_type(4))) float frag_cd;
typedef __attribute__((ext_vector_type(2))) float v2f;

__device__ __forceinline__ unsigned short f2bf(float f) {
    unsigned u = __float_as_uint(f);
    u += 0x7FFFu + ((u >> 16) & 1u);
    return (unsigned short)(u >> 16);
}
__device__ __forceinline__ float bf2f(unsigned short s) {
    return __uint_as_float(((unsigned)s) << 16);
}
// tanh for x >= 0, branch-free, ~5 VALU. |err| ~1e-6 vs absmax budget 2e-2.
__device__ __forceinline__ float fast_tanh_pos(float x) {
    float t = __expf(-2.0f * x);
    return (1.0f - t) * __builtin_amdgcn_rcpf(1.0f + t);
}

// ---------------------------------------------------------------------------
// deg_count: 1 thread/edge, global-atomic per-node degree histograms.
// Last block instead packs W into MFMA fragment layout (verified) and zeroes
// yl row n (the masked-lane zero row).
// ---------------------------------------------------------------------------
__global__ __launch_bounds__(256) void deg_count(
    const int* __restrict__ ei, int n_edges,
    int* __restrict__ deg_col, int* __restrict__ deg_row,
    const float* __restrict__ Wl, const float* __restrict__ Wr,
    unsigned short* __restrict__ wpack, unsigned* __restrict__ yl, int n)
{
    if (blockIdx.x == gridDim.x - 1) {          // pack_w + zero row
        for (int c = threadIdx.x; c < 8192; c += 256) {
            int j = c & 7;
            int lane = (c >> 3) & 63;
            int tile = (c >> 9) & 7;
            int mat = c >> 12;
            int kc = tile >> 2;
            int nt = tile & 3;
            int krow = (lane >> 4) * 8 + j + kc * 32;
            int col = (lane & 15) + nt * 16;
            const float* W = mat ? Wr : Wl;
            float v = W[krow * 64 + col];
            unsigned short hi = f2bf(v);
            unsigned short lo = f2bf(v - bf2f(hi));
            int base = mat * 8192 + tile * 512 + lane * 8 + j;
            wpack[base] = hi;
            wpack[base + 4096] = lo;
        }
        if (threadIdx.x < 32)                   // yl row n = zeros
            yl[((size_t)n << 5) + threadIdx.x] = 0u;
        return;
    }
    int i = blockIdx.x * 256 + threadIdx.x;
    if (i < n_edges) {
        int r = ei[i];
        int c = ei[n_edges + i];
        atomicAdd(&deg_row[r], 1);
        atomicAdd(&deg_col[c], 1);
    }
}

// ---------------------------------------------------------------------------
// csr_reserve: per-wave 64-bit packed prefix-sum of (deg_col | deg_row<<32),
// one wave-aggregated atomicAdd on a global cursor per order -> off + cur.
// Offsets are NON-monotonic across nodes (disjoint packing) -- consumers use
// s1 = s0 + deg, never off[node+1].
// ---------------------------------------------------------------------------
__global__ __launch_bounds__(256) void csr_reserve(
    const int* __restrict__ deg_col, const int* __restrict__ deg_row,
    int* __restrict__ gcnt,
    int* __restrict__ off_col, int* __restrict__ off_row,
    int* __restrict__ cur_col, int* __restrict__ cur_row, int n)
{
    int t = blockIdx.x * 256 + threadIdx.x;
    int lane = threadIdx.x & 63;
    unsigned dc = (t < n) ? (unsigned)deg_col[t] : 0u;
    unsigned dr = (t < n) ? (unsigned)deg_row[t] : 0u;
    unsigned long long v =
        (unsigned long long)dc | ((unsigned long long)dr << 32);
    unsigned long long x = v;
    #pragma unroll
    for (int o = 1; o < 64; o <<= 1) {
        unsigned long long u = __shfl_up(x, o);
        if (lane >= o) x += u;
    }
    unsigned long long tot = __shfl(x, 63);
    unsigned long long excl = x - v;
    unsigned long long base = 0;
    if (lane == 63) {
        unsigned bc = (unsigned)atomicAdd(&gcnt[0], (int)(tot & 0xFFFFFFFFull));
        unsigned br = (unsigned)atomicAdd(&gcnt[1], (int)(tot >> 32));
        base = (unsigned long long)bc | ((unsigned long long)br << 32);
    }
    base = __shfl(base, 63);
    if (t < n) {
        int oc  = (int)((base & 0xFFFFFFFFull) + (excl & 0xFFFFFFFFull));
        int orr = (int)((base >> 32) + (excl >> 32));
        off_col[t] = oc; cur_col[t] = oc;
        off_row[t] = orr; cur_row[t] = orr;
    }
}

// ---------------------------------------------------------------------------
// csr_scatter: 1 thread/edge, cursor atomics place each edge in its node's
// contiguous segment (order within segment arbitrary -- sums are
// order-independent). Scattered 4B writes are byte-masked in L2.
// ---------------------------------------------------------------------------
__global__ __launch_bounds__(256) void csr_scatter(
    const int* __restrict__ ei, int n_edges,
    int* __restrict__ cur_col, int* __restrict__ cur_row,
    int* __restrict__ by_col, int* __restrict__ by_row)
{
    int i = blockIdx.x * 256 + threadIdx.x;
    if (i >= n_edges) return;
    int r = ei[i];
    int c = ei[n_edges + i];
    int p = atomicAdd(&cur_col[c], 1);
    by_col[p] = r;
    int q = atomicAdd(&cur_row[r], 1);
    by_row[q] = c;
}

// ---------------------------------------------------------------------------
// gemm_x (verified R5): Yl = X@Wl (packed bf16 rows) and Yr = X@Wr + b (f32
// rows), reading X once. mean(X[rows])@Wl == mean(Yl[rows]) by linearity.
// ---------------------------------------------------------------------------
__global__ __launch_bounds__(256) void gemm_x(
    const float* __restrict__ X, const unsigned short* __restrict__ wpack,
    const float* __restrict__ b, unsigned* __restrict__ yl,
    float* __restrict__ yr, int n, int ngroups)
{
    int lane = threadIdx.x & 63;
    int g = (blockIdx.x * blockDim.x + threadIdx.x) >> 6;
    if (g >= ngroups) return;
    int quad = lane >> 4;
    int l15 = lane & 15;

    frag_ab wf[2][2][2][4];
    #pragma unroll
    for (int mat = 0; mat < 2; ++mat)
        #pragma unroll
        for (int hf = 0; hf < 2; ++hf)
            #pragma unroll
            for (int kc = 0; kc < 2; ++kc)
                #pragma unroll
                for (int nt = 0; nt < 4; ++nt) {
                    const unsigned short* p =
                        wpack + mat * 8192 + hf * 4096 + (kc * 4 + nt) * 512 + lane * 8;
                    wf[mat][hf][kc][nt] = *(const frag_ab*)p;
                }

    frag_cd accl[4], accr[4];
    #pragma unroll
    for (int nt = 0; nt < 4; ++nt) {
        accl[nt] = (frag_cd){0.f, 0.f, 0.f, 0.f};
        accr[nt] = (frag_cd){0.f, 0.f, 0.f, 0.f};
    }

    int mrow = g * 16 + l15;
    if (mrow >= n) mrow = n - 1;
    const float* xrow = X + ((size_t)mrow << 6) + quad * 8;

    #pragma unroll
    for (int kc = 0; kc < 2; ++kc) {
        float xv[8];
        #pragma unroll
        for (int t = 0; t < 2; ++t) {
            float4 x4 = *(const float4*)(xrow + kc * 32 + t * 4);
            xv[t * 4 + 0] = x4.x; xv[t * 4 + 1] = x4.y;
            xv[t * 4 + 2] = x4.z; xv[t * 4 + 3] = x4.w;
        }
        frag_ab xh, xl;
        #pragma unroll
        for (int j = 0; j < 8; ++j) {
            unsigned short xbv = f2bf(xv[j]);
            xh[j] = (short)xbv;
            xl[j] = (short)f2bf(xv[j] - bf2f(xbv));
        }
        #pragma unroll
        for (int nt = 0; nt < 4; ++nt) {
            accl[nt] = __builtin_amdgcn_mfma_f32_16x16x32_bf16(xh, wf[0][0][kc][nt], accl[nt], 0, 0, 0);
            accl[nt] = __builtin_amdgcn_mfma_f32_16x16x32_bf16(xh, wf[0][1][kc][nt], accl[nt], 0, 0, 0);
            accl[nt] = __builtin_amdgcn_mfma_f32_16x16x32_bf16(xl, wf[0][0][kc][nt], accl[nt], 0, 0, 0);
            accr[nt] = __builtin_amdgcn_mfma_f32_16x16x32_bf16(xh, wf[1][0][kc][nt], accr[nt], 0, 0, 0);
            accr[nt] = __builtin_amdgcn_mfma_f32_16x16x32_bf16(xh, wf[1][1][kc][nt], accr[nt], 0, 0, 0);
            accr[nt] = __builtin_amdgcn_mfma_f32_16x16x32_bf16(xl, wf[1][0][kc][nt], accr[nt], 0, 0, 0);
        }
    }

    #pragma unroll
    for (int nt = 0; nt < 4; ++nt) {
        float bj = b[l15 + nt * 16];
        #pragma unroll
        for (int r = 0; r < 4; ++r) {
            int row = quad * 4 + r;
            int node = g * 16 + row;
            float vl = accl[nt][r];
            float vr = accr[nt][r] + bj;
            float vln = __shfl_xor(vl, 1);    // neighbor feature (l15^1)
            if (node < n) {
                yr[((size_t)node << 6) + nt * 16 + l15] = vr;
                if ((l15 & 1) == 0) {
                    unsigned pk = (unsigned)f2bf(vl) | ((unsigned)f2bf(vln) << 16);
                    yl[((size_t)node << 5) + nt * 8 + (l15 >> 1)] = pk;
                }
            }
        }
    }
}

// ---------------------------------------------------------------------------
// h_gather (verified R5 body): 16 lanes/edge, uint2 loads, p-unroll 4,
// branch-free, packed-fp32 accumulate; epilogue finishes
// h = relu(mean + Yr) -> packed-bf16 hb. s1 = s0 + deg (atomic CSR).
// ---------------------------------------------------------------------------
__global__ __launch_bounds__(256) void h_gather(
    const unsigned* __restrict__ yl, const float* __restrict__ yr,
    const int* __restrict__ off_col, const int* __restrict__ deg_col,
    const int* __restrict__ by_col, unsigned* __restrict__ hb, int n)
{
    int lane = threadIdx.x & 63;
    int node = (blockIdx.x * blockDim.x + threadIdx.x) >> 6;
    if (node >= n) return;
    int fl = lane & 15, q = lane >> 4;
    int s0 = off_col[node];
    int s1 = s0 + deg_col[node];
    v2f a01 = {0.f, 0.f}, a23 = {0.f, 0.f};
    for (int base = s0; base < s1; base += 64) {
        int m = s1 - base;
        if (m > 64) m = 64;
        int idx = (lane < m) ? by_col[base + lane] : n;   // row n = zeros
        for (int j = 0; j < m; j += 16) {
            #pragma unroll
            for (int p = 0; p < 4; ++p) {
                int jj = j + 4 * p + q;                   // <= 63 always
                int e = __shfl(idx, jj);
                uint2 v = ((const uint2*)yl)[((size_t)e << 4) + fl];
                v2f h01, h23;
                h01.x = __uint_as_float(v.x << 16);
                h01.y = __uint_as_float(v.x & 0xFFFF0000u);
                h23.x = __uint_as_float(v.y << 16);
                h23.y = __uint_as_float(v.y & 0xFFFF0000u);
                a01 += h01;                               // v_pk_add_f32
                a23 += h23;
            }
        }
    }
    a01.x += __shfl_xor(a01.x, 16); a01.x += __shfl_xor(a01.x, 32);
    a01.y += __shfl_xor(a01.y, 16); a01.y += __shfl_xor(a01.y, 32);
    a23.x += __shfl_xor(a23.x, 16); a23.x += __shfl_xor(a23.x, 32);
    a23.y += __shfl_xor(a23.y, 16); a23.y += __shfl_xor(a23.y, 32);
    if (lane < 16) {
        float inv = 1.f / fmaxf((float)(s1 - s0), 1.f);
        float4 yv = ((const float4*)yr)[((size_t)node << 4) + fl];
        float h0 = fmaxf(a01.x * inv + yv.x, 0.f);
        float h1 = fmaxf(a01.y * inv + yv.y, 0.f);
        float h2 = fmaxf(a23.x * inv + yv.z, 0.f);
        float h3 = fmaxf(a23.y * inv + yv.w, 0.f);
        uint2 pk;
        pk.x = (unsigned)f2bf(h0) | ((unsigned)f2bf(h1) << 16);
        pk.y = (unsigned)f2bf(h2) | ((unsigned)f2bf(h3) << 16);
        ((uint2*)hb)[((size_t)node << 4) + fl] = pk;
    }
}

// ---------------------------------------------------------------------------
// Gate (verified R5 body): 16 lanes/edge, branch-free (masked -> self,
// d = 0 exactly), packed-fp32 math, fast tanh. s1 = s0 + deg (atomic CSR).
// ---------------------------------------------------------------------------
__global__ __launch_bounds__(256) void gate_kernel(
    const unsigned* __restrict__ hb, const int* __restrict__ off_row,
    const int* __restrict__ deg_row, const int* __restrict__ by_row,
    float* __restrict__ out, int n)
{
    int lane = threadIdx.x & 63;
    int u = (blockIdx.x * blockDim.x + threadIdx.x) >> 6;
    if (u >= n) return;
    int fl = lane & 15, q = lane >> 4;
    int s0 = off_row[u];
    int s1 = s0 + deg_row[u];
    uint2 hp = ((const uint2*)hb)[((size_t)u << 4) + fl];
    v2f f01, f23;
    f01.x = __uint_as_float(hp.x << 16);
    f01.y = __uint_as_float(hp.x & 0xFFFF0000u);
    f23.x = __uint_as_float(hp.y << 16);
    f23.y = __uint_as_float(hp.y & 0xFFFF0000u);
    v2f a01 = {0.f, 0.f}, a23 = {0.f, 0.f};
    for (int base = s0; base < s1; base += 64) {
        int m = s1 - base;
        if (m > 64) m = 64;
        int idx = (lane < m) ? by_row[base + lane] : u;   // self -> d = 0
        for (int j = 0; j < m; j += 16) {
            #pragma unroll
            for (int p = 0; p < 4; ++p) {
                int jj = j + 4 * p + q;                   // <= 63 always
                int e = __shfl(idx, jj);
                uint2 v = ((const uint2*)hb)[((size_t)e << 4) + fl];
                v2f h01, h23;
                h01.x = __uint_as_float(v.x << 16);
                h01.y = __uint_as_float(v.x & 0xFFFF0000u);
                h23.x = __uint_as_float(v.y << 16);
                h23.y = __uint_as_float(v.y & 0xFFFF0000u);
                v2f d01 = f01 - h01;                      // v_pk_add (neg)
                v2f d23 = f23 - h23;
                a01 += d01 * d01;                         // v_pk_fma
                a23 += d23 * d23;
            }
        }
    }
    a01.x += __shfl_xor(a01.x, 16); a01.x += __shfl_xor(a01.x, 32);
    a01.y += __shfl_xor(a01.y, 16); a01.y += __shfl_xor(a01.y, 32);
    a23.x += __shfl_xor(a23.x, 16); a23.x += __shfl_xor(a23.x, 32);
    a23.y += __shfl_xor(a23.y, 16); a23.y += __shfl_xor(a23.y, 32);
    if (lane < 16) {
        float inv = 1.f / fmaxf((float)(s1 - s0), 1.f);
        float4 o;
        o.x = fast_tanh_pos(a01.x * inv);
        o.y = fast_tanh_pos(a01.y * inv);
        o.z = fast_tanh_pos(a23.x * inv);
        o.w = fast_tanh_pos(a23.y * inv);
        ((float4*)out)[((size_t)u << 4) + fl] = o;
    }
}

extern "C" void kernel_launch(void* const* d_in, const int* in_sizes, int n_in,
                              void* d_out, int out_size, void* d_ws, size_t ws_size,
                              hipStream_t stream) {
    const float* X  = (const float*)d_in[0];
    const int*   ei = (const int*)d_in[1];
    const float* Wl = (const float*)d_in[2];
    const float* Wr = (const float*)d_in[3];
    const float* b  = (const float*)d_in[4];
    float* out = (float*)d_out;

    int n = in_sizes[0] / D;
    int n_edges = in_sizes[1] / 2;

    // ws layout (~64 MB); yl has n+1 rows (row n = zeros)
    float* yr = (float*)d_ws;                                  // n*64 f32
    unsigned* yl = (unsigned*)(yr + (size_t)n * D);            // (n+1)*32 u32
    unsigned* hb = yl + (size_t)(n + 1) * 32;                  // n*32 u32
    unsigned short* wpack = (unsigned short*)(hb + (size_t)n * 32); // 16384
    int* w = (int*)(wpack + 16384);
    int* deg_col = w;                      // n
    int* deg_row = deg_col + n;            // n
    int* gcnt    = deg_row + n;            // 2
    int* off_col = gcnt + 2;               // n
    int* off_row = off_col + n;            // n
    int* cur_col = off_row + n;            // n
    int* cur_row = cur_col + n;            // n
    int* by_col  = cur_row + n;            // n_edges
    int* by_row  = by_col + n_edges;       // n_edges

    // zero deg_col, deg_row, gcnt (contiguous)
    (void)hipMemsetAsync(deg_col, 0, (size_t)(2 * n + 2) * sizeof(int), stream);

    int nb_e = (n_edges + 255) / 256;
    deg_count<<<nb_e + 1, 256, 0, stream>>>(ei, n_edges, deg_col, deg_row,
                                            Wl, Wr, wpack, yl, n);
    csr_reserve<<<(n + 255) / 256, 256, 0, stream>>>(
        deg_col, deg_row, gcnt, off_col, off_row, cur_col, cur_row, n);
    csr_scatter<<<nb_e, 256, 0, stream>>>(ei, n_edges, cur_col, cur_row,
                                          by_col, by_row);

    int ngroups = (n + 15) / 16;
    gemm_x<<<(ngroups + 3) / 4, 256, 0, stream>>>(X, wpack, b, yl, yr, n, ngroups);

    h_gather<<<(n + 3) / 4, 256, 0, stream>>>(yl, yr, off_col, deg_col,
                                              by_col, hb, n);
    gate_kernel<<<(n + 3) / 4, 256, 0, stream>>>(hb, off_row, deg_row,
                                                 by_row, out, n);
}

// Round 7
// 222.554 us; speedup vs baseline: 2.3459x; 2.3459x over previous
//
#include <hip/hip_runtime.h>
#include <math.h>

#define D 64
#define CHUNK 8192
#define MS_T 1024
#define EPT 8           // CHUNK / MS_T
#define MAXNB 800       // >= nbk = ceil(n/128); n=100000 -> 782

typedef __attribute__((ext_vector_type(8))) short frag_ab;
typedef __attribute__((ext_vector_type(4))) float frag_cd;
typedef __attribute__((ext_vector_type(2))) float v2f;

__device__ __forceinline__ unsigned short f2bf(float f) {
    unsigned u = __float_as_uint(f);
    u += 0x7FFFu + ((u >> 16) & 1u);
    return (unsigned short)(u >> 16);
}
__device__ __forceinline__ float bf2f(unsigned short s) {
    return __uint_as_float(((unsigned)s) << 16);
}
// tanh for x >= 0, branch-free, ~5 VALU. |err| ~1e-6 vs absmax budget 2e-2.
__device__ __forceinline__ float fast_tanh_pos(float x) {
    float t = __expf(-2.0f * x);
    return (1.0f - t) * __builtin_amdgcn_rcpf(1.0f + t);
}

// ---------------------------------------------------------------------------
// bucket_hist: per-chunk LDS histogram over 128-node buckets (verified).
// Last block instead packs W into MFMA fragment layout (verified) and zeroes
// yl row n (the masked-lane zero row).
// ---------------------------------------------------------------------------
__global__ __launch_bounds__(MS_T) void bucket_hist(
    const int* __restrict__ ei, int n_edges, int nbk,
    int* __restrict__ bc_col, int* __restrict__ bc_row,
    const float* __restrict__ Wl, const float* __restrict__ Wr,
    unsigned short* __restrict__ wpack, unsigned* __restrict__ yl, int n)
{
    __shared__ int scol[MAXNB];
    __shared__ int srow[MAXNB];

    if (blockIdx.x == gridDim.x - 1) {          // pack_w + zero row
        if (threadIdx.x < 256) {
            for (int c = threadIdx.x; c < 8192; c += 256) {
                int j = c & 7;
                int lane = (c >> 3) & 63;
                int tile = (c >> 9) & 7;
                int mat = c >> 12;
                int kc = tile >> 2;
                int nt = tile & 3;
                int krow = (lane >> 4) * 8 + j + kc * 32;
                int col = (lane & 15) + nt * 16;
                const float* W = mat ? Wr : Wl;
                float v = W[krow * 64 + col];
                unsigned short hi = f2bf(v);
                unsigned short lo = f2bf(v - bf2f(hi));
                int base = mat * 8192 + tile * 512 + lane * 8 + j;
                wpack[base] = hi;
                wpack[base + 4096] = lo;
            }
            if (threadIdx.x < 32)               // yl row n = zeros
                yl[((size_t)n << 5) + threadIdx.x] = 0u;
        }
        return;
    }

    for (int t = threadIdx.x; t < nbk; t += MS_T) {
        scol[t] = 0;
        srow[t] = 0;
    }
    __syncthreads();

    int base = blockIdx.x * CHUNK;
    int cc = n_edges - base;
    if (cc > CHUNK) cc = CHUNK;
    #pragma unroll
    for (int k = 0; k < EPT; ++k) {
        int i = threadIdx.x + k * MS_T;
        if (i < cc) {
            int r = ei[base + i];
            int c = ei[n_edges + base + i];
            atomicAdd(&srow[r >> 7], 1);
            atomicAdd(&scol[c >> 7], 1);
        }
    }
    __syncthreads();
    for (int t = threadIdx.x; t < nbk; t += MS_T) {
        if (scol[t]) atomicAdd(&bc_col[t], scol[t]);
        if (srow[t]) atomicAdd(&bc_row[t], srow[t]);
    }
}

// ---------------------------------------------------------------------------
// bucket_scan: ONE 1024-thread block, wave-scan + cross-wave LDS scan
// (R6: replaces the 64-thread serial-loop version; nbk=782 <= 1024).
// ---------------------------------------------------------------------------
__global__ __launch_bounds__(1024) void bucket_scan(
    const int* __restrict__ bc_col, const int* __restrict__ bc_row,
    int* __restrict__ bbase_col, int* __restrict__ bbase_row,
    int* __restrict__ gcur_col, int* __restrict__ gcur_row, int nbk)
{
    __shared__ int wsum[16];
    int tid = threadIdx.x, lane = tid & 63, w = tid >> 6;
    for (int ord = 0; ord < 2; ++ord) {
        const int* bc = ord ? bc_row : bc_col;
        int* bb = ord ? bbase_row : bbase_col;
        int* gc = ord ? gcur_row : gcur_col;
        int v = (tid < nbk) ? bc[tid] : 0;
        int x = v;
        #pragma unroll
        for (int o = 1; o < 64; o <<= 1) {
            int u = __shfl_up(x, o);
            if (lane >= o) x += u;
        }
        if (lane == 63) wsum[w] = x;
        __syncthreads();
        if (tid < 64) {
            int s = (tid < 16) ? wsum[tid] : 0;
            #pragma unroll
            for (int o = 1; o < 16; o <<= 1) {
                int u = __shfl_up(s, o);
                if (lane >= o) s += u;
            }
            if (tid < 16) wsum[tid] = s;        // inclusive wave sums
        }
        __syncthreads();
        int base = (w > 0) ? wsum[w - 1] : 0;
        if (tid < nbk) {
            int e = base + x - v;               // exclusive scan
            bb[tid] = e;
            gc[tid] = e;
        }
        __syncthreads();
    }
}

// ---------------------------------------------------------------------------
// Multisplit (verified R5 body; R6: one ORDER per block, grid = 2*nchunks,
// so the two independent orders run concurrently instead of sequentially).
// ---------------------------------------------------------------------------
__global__ __launch_bounds__(MS_T) void multisplit(
    const int* __restrict__ ei, int n_edges, int nbk, int nchunks,
    int* __restrict__ gcur_col, int* __restrict__ gcur_row,
    unsigned* __restrict__ ecol, unsigned* __restrict__ erow)
{
    __shared__ unsigned stage[CHUNK];
    __shared__ unsigned short sbk[CHUNK];
    __shared__ int cnt[MAXNB];
    __shared__ int off[MAXNB + 1];
    __shared__ int gb[MAXNB];

    int ord = blockIdx.x >= (unsigned)nchunks;
    int chunk = ord ? (blockIdx.x - nchunks) : blockIdx.x;
    int base = chunk * CHUNK;
    int cc = n_edges - base;
    if (cc > CHUNK) cc = CHUNK;

    int* gcur = ord ? gcur_row : gcur_col;
    unsigned* eout = ord ? erow : ecol;

    int key[EPT], oth[EPT];
    #pragma unroll
    for (int k = 0; k < EPT; ++k) {
        int i = threadIdx.x + k * MS_T;
        if (i < cc) {
            int r = ei[base + i];
            int c = ei[n_edges + base + i];
            key[k] = ord ? r : c;
            oth[k] = ord ? c : r;
        }
    }

    for (int t = threadIdx.x; t < nbk; t += MS_T) cnt[t] = 0;
    __syncthreads();

    int rk[EPT], bk[EPT];
    #pragma unroll
    for (int k = 0; k < EPT; ++k) {
        int i = threadIdx.x + k * MS_T;
        if (i < cc) {
            bk[k] = key[k] >> 7;
            rk[k] = atomicAdd(&cnt[bk[k]], 1);
        }
    }
    __syncthreads();

    if (threadIdx.x < 64) {               // wave 0: scan + global reservation
        int lane = threadIdx.x;
        int carry = 0;
        for (int b0 = 0; b0 < nbk; b0 += 64) {
            int v = (b0 + lane < nbk) ? cnt[b0 + lane] : 0;
            int x = v;
            #pragma unroll
            for (int o = 1; o < 64; o <<= 1) {
                int u = __shfl_up(x, o);
                if (lane >= o) x += u;
            }
            if (b0 + lane < nbk) {
                off[b0 + lane] = carry + x - v;
                gb[b0 + lane] = v ? atomicAdd(&gcur[b0 + lane], v) : 0;
            }
            carry += __shfl(x, 63);
        }
    }
    __syncthreads();

    #pragma unroll
    for (int k = 0; k < EPT; ++k) {
        int i = threadIdx.x + k * MS_T;
        if (i < cc) {
            int p = off[bk[k]] + rk[k];
            stage[p] = ((unsigned)(key[k] & 127) << 17) | (unsigned)oth[k];
            sbk[p] = (unsigned short)bk[k];
        }
    }
    __syncthreads();

    for (int t = threadIdx.x; t < cc; t += MS_T) {
        int bb = sbk[t];
        eout[gb[bb] + (t - off[bb])] = stage[t];
    }
}

// ---------------------------------------------------------------------------
// csr_build (verified): bucket entries -> exact per-node CSR.
// ---------------------------------------------------------------------------
__global__ __launch_bounds__(256) void csr_build(
    const unsigned* __restrict__ ecol, const unsigned* __restrict__ erow,
    const int* __restrict__ bbase_col, const int* __restrict__ bbase_row,
    const int* __restrict__ bc_col, const int* __restrict__ bc_row,
    int* __restrict__ off_col, int* __restrict__ off_row,
    int* __restrict__ by_col, int* __restrict__ by_row, int n, int nbk)
{
    __shared__ int scnt[128];
    __shared__ int soff[129];
    bool isRow = blockIdx.x >= (unsigned)nbk;
    int b = isRow ? (blockIdx.x - nbk) : blockIdx.x;
    const unsigned* e = isRow ? erow : ecol;
    int base = (isRow ? bbase_row : bbase_col)[b];
    int ec = (isRow ? bc_row : bc_col)[b];
    int* off_g = isRow ? off_row : off_col;
    int* by = isRow ? by_row : by_col;

    int node0 = b << 7;
    int nn = n - node0;
    if (nn > 128) nn = 128;

    if (threadIdx.x < 128) scnt[threadIdx.x] = 0;
    __syncthreads();

    for (int t = threadIdx.x; t < ec; t += 256)
        atomicAdd(&scnt[e[base + t] >> 17], 1);
    __syncthreads();

    if (threadIdx.x < 64) {
        int lane = threadIdx.x;
        int carry = 0;
        #pragma unroll
        for (int b0 = 0; b0 < 128; b0 += 64) {
            int v = scnt[b0 + lane];
            int x = v;
            #pragma unroll
            for (int o = 1; o < 64; o <<= 1) {
                int u = __shfl_up(x, o);
                if (lane >= o) x += u;
            }
            soff[b0 + lane] = carry + x - v;
            carry += __shfl(x, 63);
        }
        if (lane == 63) soff[128] = carry;
    }
    __syncthreads();

    if (threadIdx.x < 128) {
        if (threadIdx.x < nn) off_g[node0 + threadIdx.x] = base + soff[threadIdx.x];
        scnt[threadIdx.x] = 0;
    }
    if (threadIdx.x == 0 && node0 + nn == n) off_g[n] = base + soff[nn];
    __syncthreads();

    for (int t = threadIdx.x; t < ec; t += 256) {
        unsigned ent = e[base + t];
        int slot = ent >> 17;
        int r = atomicAdd(&scnt[slot], 1);
        by[base + soff[slot] + r] = (int)(ent & 0x1FFFF);
    }
}

// ---------------------------------------------------------------------------
// gemm_x (verified R5): Yl = X@Wl (packed bf16 rows) and Yr = X@Wr + b (f32
// rows), reading X once. mean(X[rows])@Wl == mean(Yl[rows]) by linearity.
// ---------------------------------------------------------------------------
__global__ __launch_bounds__(256) void gemm_x(
    const float* __restrict__ X, const unsigned short* __restrict__ wpack,
    const float* __restrict__ b, unsigned* __restrict__ yl,
    float* __restrict__ yr, int n, int ngroups)
{
    int lane = threadIdx.x & 63;
    int g = (blockIdx.x * blockDim.x + threadIdx.x) >> 6;
    if (g >= ngroups) return;
    int quad = lane >> 4;
    int l15 = lane & 15;

    frag_ab wf[2][2][2][4];
    #pragma unroll
    for (int mat = 0; mat < 2; ++mat)
        #pragma unroll
        for (int hf = 0; hf < 2; ++hf)
            #pragma unroll
            for (int kc = 0; kc < 2; ++kc)
                #pragma unroll
                for (int nt = 0; nt < 4; ++nt) {
                    const unsigned short* p =
                        wpack + mat * 8192 + hf * 4096 + (kc * 4 + nt) * 512 + lane * 8;
                    wf[mat][hf][kc][nt] = *(const frag_ab*)p;
                }

    frag_cd accl[4], accr[4];
    #pragma unroll
    for (int nt = 0; nt < 4; ++nt) {
        accl[nt] = (frag_cd){0.f, 0.f, 0.f, 0.f};
        accr[nt] = (frag_cd){0.f, 0.f, 0.f, 0.f};
    }

    int mrow = g * 16 + l15;
    if (mrow >= n) mrow = n - 1;
    const float* xrow = X + ((size_t)mrow << 6) + quad * 8;

    #pragma unroll
    for (int kc = 0; kc < 2; ++kc) {
        float xv[8];
        #pragma unroll
        for (int t = 0; t < 2; ++t) {
            float4 x4 = *(const float4*)(xrow + kc * 32 + t * 4);
            xv[t * 4 + 0] = x4.x; xv[t * 4 + 1] = x4.y;
            xv[t * 4 + 2] = x4.z; xv[t * 4 + 3] = x4.w;
        }
        frag_ab xh, xl;
        #pragma unroll
        for (int j = 0; j < 8; ++j) {
            unsigned short xbv = f2bf(xv[j]);
            xh[j] = (short)xbv;
            xl[j] = (short)f2bf(xv[j] - bf2f(xbv));
        }
        #pragma unroll
        for (int nt = 0; nt < 4; ++nt) {
            accl[nt] = __builtin_amdgcn_mfma_f32_16x16x32_bf16(xh, wf[0][0][kc][nt], accl[nt], 0, 0, 0);
            accl[nt] = __builtin_amdgcn_mfma_f32_16x16x32_bf16(xh, wf[0][1][kc][nt], accl[nt], 0, 0, 0);
            accl[nt] = __builtin_amdgcn_mfma_f32_16x16x32_bf16(xl, wf[0][0][kc][nt], accl[nt], 0, 0, 0);
            accr[nt] = __builtin_amdgcn_mfma_f32_16x16x32_bf16(xh, wf[1][0][kc][nt], accr[nt], 0, 0, 0);
            accr[nt] = __builtin_amdgcn_mfma_f32_16x16x32_bf16(xh, wf[1][1][kc][nt], accr[nt], 0, 0, 0);
            accr[nt] = __builtin_amdgcn_mfma_f32_16x16x32_bf16(xl, wf[1][0][kc][nt], accr[nt], 0, 0, 0);
        }
    }

    #pragma unroll
    for (int nt = 0; nt < 4; ++nt) {
        float bj = b[l15 + nt * 16];
        #pragma unroll
        for (int r = 0; r < 4; ++r) {
            int row = quad * 4 + r;
            int node = g * 16 + row;
            float vl = accl[nt][r];
            float vr = accr[nt][r] + bj;
            float vln = __shfl_xor(vl, 1);    // neighbor feature (l15^1)
            if (node < n) {
                yr[((size_t)node << 6) + nt * 16 + l15] = vr;
                if ((l15 & 1) == 0) {
                    unsigned pk = (unsigned)f2bf(vl) | ((unsigned)f2bf(vln) << 16);
                    yl[((size_t)node << 5) + nt * 8 + (l15 >> 1)] = pk;
                }
            }
        }
    }
}

// ---------------------------------------------------------------------------
// h_gather (verified R5 body): 16 lanes/edge, uint2 loads, p-unroll 4,
// branch-free, packed-fp32 accumulate; epilogue finishes
// h = relu(mean + Yr) -> packed-bf16 hb.
// ---------------------------------------------------------------------------
__global__ __launch_bounds__(256) void h_gather(
    const unsigned* __restrict__ yl, const float* __restrict__ yr,
    const int* __restrict__ off_col, const int* __restrict__ by_col,
    unsigned* __restrict__ hb, int n)
{
    int lane = threadIdx.x & 63;
    int node = (blockIdx.x * blockDim.x + threadIdx.x) >> 6;
    if (node >= n) return;
    int fl = lane & 15, q = lane >> 4;
    int s0 = off_col[node], s1 = off_col[node + 1];
    v2f a01 = {0.f, 0.f}, a23 = {0.f, 0.f};
    for (int base = s0; base < s1; base += 64) {
        int m = s1 - base;
        if (m > 64) m = 64;
        int idx = (lane < m) ? by_col[base + lane] : n;   // row n = zeros
        for (int j = 0; j < m; j += 16) {
            #pragma unroll
            for (int p = 0; p < 4; ++p) {
                int jj = j + 4 * p + q;                   // <= 63 always
                int e = __shfl(idx, jj);
                uint2 v = ((const uint2*)yl)[((size_t)e << 4) + fl];
                v2f h01, h23;
                h01.x = __uint_as_float(v.x << 16);
                h01.y = __uint_as_float(v.x & 0xFFFF0000u);
                h23.x = __uint_as_float(v.y << 16);
                h23.y = __uint_as_float(v.y & 0xFFFF0000u);
                a01 += h01;                               // v_pk_add_f32
                a23 += h23;
            }
        }
    }
    a01.x += __shfl_xor(a01.x, 16); a01.x += __shfl_xor(a01.x, 32);
    a01.y += __shfl_xor(a01.y, 16); a01.y += __shfl_xor(a01.y, 32);
    a23.x += __shfl_xor(a23.x, 16); a23.x += __shfl_xor(a23.x, 32);
    a23.y += __shfl_xor(a23.y, 16); a23.y += __shfl_xor(a23.y, 32);
    if (lane < 16) {
        float inv = 1.f / fmaxf((float)(s1 - s0), 1.f);
        float4 yv = ((const float4*)yr)[((size_t)node << 4) + fl];
        float h0 = fmaxf(a01.x * inv + yv.x, 0.f);
        float h1 = fmaxf(a01.y * inv + yv.y, 0.f);
        float h2 = fmaxf(a23.x * inv + yv.z, 0.f);
        float h3 = fmaxf(a23.y * inv + yv.w, 0.f);
        uint2 pk;
        pk.x = (unsigned)f2bf(h0) | ((unsigned)f2bf(h1) << 16);
        pk.y = (unsigned)f2bf(h2) | ((unsigned)f2bf(h3) << 16);
        ((uint2*)hb)[((size_t)node << 4) + fl] = pk;
    }
}

// ---------------------------------------------------------------------------
// Gate (verified R5 body): 16 lanes/edge, branch-free (masked -> self,
// d = 0 exactly), packed-fp32 math, fast tanh.
// ---------------------------------------------------------------------------
__global__ __launch_bounds__(256) void gate_kernel(
    const unsigned* __restrict__ hb, const int* __restrict__ off_row,
    const int* __restrict__ by_row, float* __restrict__ out, int n)
{
    int lane = threadIdx.x & 63;
    int u = (blockIdx.x * blockDim.x + threadIdx.x) >> 6;
    if (u >= n) return;
    int fl = lane & 15, q = lane >> 4;
    int s0 = off_row[u], s1 = off_row[u + 1];
    uint2 hp = ((const uint2*)hb)[((size_t)u << 4) + fl];
    v2f f01, f23;
    f01.x = __uint_as_float(hp.x << 16);
    f01.y = __uint_as_float(hp.x & 0xFFFF0000u);
    f23.x = __uint_as_float(hp.y << 16);
    f23.y = __uint_as_float(hp.y & 0xFFFF0000u);
    v2f a01 = {0.f, 0.f}, a23 = {0.f, 0.f};
    for (int base = s0; base < s1; base += 64) {
        int m = s1 - base;
        if (m > 64) m = 64;
        int idx = (lane < m) ? by_row[base + lane] : u;   // self -> d = 0
        for (int j = 0; j < m; j += 16) {
            #pragma unroll
            for (int p = 0; p < 4; ++p) {
                int jj = j + 4 * p + q;                   // <= 63 always
                int e = __shfl(idx, jj);
                uint2 v = ((const uint2*)hb)[((size_t)e << 4) + fl];
                v2f h01, h23;
                h01.x = __uint_as_float(v.x << 16);
                h01.y = __uint_as_float(v.x & 0xFFFF0000u);
                h23.x = __uint_as_float(v.y << 16);
                h23.y = __uint_as_float(v.y & 0xFFFF0000u);
                v2f d01 = f01 - h01;                      // v_pk_add (neg)
                v2f d23 = f23 - h23;
                a01 += d01 * d01;                         // v_pk_fma
                a23 += d23 * d23;
            }
        }
    }
    a01.x += __shfl_xor(a01.x, 16); a01.x += __shfl_xor(a01.x, 32);
    a01.y += __shfl_xor(a01.y, 16); a01.y += __shfl_xor(a01.y, 32);
    a23.x += __shfl_xor(a23.x, 16); a23.x += __shfl_xor(a23.x, 32);
    a23.y += __shfl_xor(a23.y, 16); a23.y += __shfl_xor(a23.y, 32);
    if (lane < 16) {
        float inv = 1.f / fmaxf((float)(s1 - s0), 1.f);
        float4 o;
        o.x = fast_tanh_pos(a01.x * inv);
        o.y = fast_tanh_pos(a01.y * inv);
        o.z = fast_tanh_pos(a23.x * inv);
        o.w = fast_tanh_pos(a23.y * inv);
        ((float4*)out)[((size_t)u << 4) + fl] = o;
    }
}

extern "C" void kernel_launch(void* const* d_in, const int* in_sizes, int n_in,
                              void* d_out, int out_size, void* d_ws, size_t ws_size,
                              hipStream_t stream) {
    const float* X  = (const float*)d_in[0];
    const int*   ei = (const int*)d_in[1];
    const float* Wl = (const float*)d_in[2];
    const float* Wr = (const float*)d_in[3];
    const float* b  = (const float*)d_in[4];
    float* out = (float*)d_out;

    int n = in_sizes[0] / D;
    int n_edges = in_sizes[1] / 2;
    int nbk = (n + 127) >> 7;
    int nchunks = (n_edges + CHUNK - 1) / CHUNK;

    // ws layout (~72 MB); yl has n+1 rows (row n = zeros)
    float* yr = (float*)d_ws;                                  // n*64 f32
    unsigned* yl = (unsigned*)(yr + (size_t)n * D);            // (n+1)*32 u32
    unsigned* hb = yl + (size_t)(n + 1) * 32;                  // n*32 u32
    unsigned short* wpack = (unsigned short*)(hb + (size_t)n * 32); // 16384
    int* w = (int*)(wpack + 16384);
    int* bc_col    = w;                    // nbk
    int* bc_row    = bc_col + nbk;         // nbk
    int* bbase_col = bc_row + nbk;         // nbk
    int* bbase_row = bbase_col + nbk;      // nbk
    int* gcur_col  = bbase_row + nbk;      // nbk
    int* gcur_row  = gcur_col + nbk;       // nbk
    int* off_col   = gcur_row + nbk;       // n+1
    int* off_row   = off_col + (n + 1);    // n+1
    unsigned* ecol = (unsigned*)(off_row + (n + 1));   // n_edges
    unsigned* erow = ecol + n_edges;                   // n_edges
    int* by_col = (int*)(erow + n_edges);              // n_edges
    int* by_row = by_col + n_edges;                    // n_edges

    (void)hipMemsetAsync(bc_col, 0, (size_t)2 * nbk * sizeof(int), stream);

    bucket_hist<<<nchunks + 1, MS_T, 0, stream>>>(ei, n_edges, nbk, bc_col, bc_row,
                                                  Wl, Wr, wpack, yl, n);
    bucket_scan<<<1, 1024, 0, stream>>>(bc_col, bc_row, bbase_col, bbase_row,
                                        gcur_col, gcur_row, nbk);
    multisplit<<<2 * nchunks, MS_T, 0, stream>>>(ei, n_edges, nbk, nchunks,
                                                 gcur_col, gcur_row, ecol, erow);
    csr_build<<<2 * nbk, 256, 0, stream>>>(ecol, erow, bbase_col, bbase_row,
                                           bc_col, bc_row, off_col, off_row,
                                           by_col, by_row, n, nbk);

    int ngroups = (n + 15) / 16;
    gemm_x<<<(ngroups + 3) / 4, 256, 0, stream>>>(X, wpack, b, yl, yr, n, ngroups);

    h_gather<<<(n + 3) / 4, 256, 0, stream>>>(yl, yr, off_col, by_col, hb, n);
    gate_kernel<<<(n + 3) / 4, 256, 0, stream>>>(hb, off_row, by_row, out, n);
}